// Round 6
// baseline (169.808 us; speedup 1.0000x reference)
//
#include <hip/hip_runtime.h>
#include <hip/hip_bf16.h>

// PCGraphConv: iterative predictive-coding message passing.
// N_V=2000, N_SENS=784, N_E=500000, BATCH=32, T=5, lr=0.1.
// R18: SINGLE persistent kernel. R17's chain (4 launches, ~92us) is folded
// into the proven persistent loop as phases separated by the proven
// fence-free gbar (~1-2us): init+hist -> scan -> place -> build -> stage ->
// 5-step loop. Coherence discipline (all HW-verified in R15/R17):
//  - cross-block mutable data (cnt_g/base_g/totals/pk_g/WAdT/fxA/errA/
//    v_cur/out) is sc1-ONLY (relaxed agent atomics -> LLC-coherent, no
//    wbl2/inv). No 64B line mixes normal-dirty + sc1 writes.
//  - WAbf: written & re-read by the SAME block -> normal cached ops.
//  - LDS union: build acc[16][2016] (129KB) aliases loop WldsA+WldsB
//    (129KB); acc fully consumed before gbar(4), staging overwrites after.
// Dispatches: k_zero_i32 (bar) + k_all.
// Fallback: proven R4 CSR path if ws too small.

#define N_V     2000
#define N_SENS  784
#define N_INT   (N_V - N_SENS)   // 1216
#define N_E     500000
#define T_STEPS 5
#define LR_VAL  0.1f
#define NVB     (N_V * 32)       // 64000
#define NVH     (N_V * 16)       // 32000
#define KP      2016             // padded K (63 chunks of 32)
#define NCH     63               // K chunks
#define NT1     125              // dst tiles (125*16 = 2000)
#define NT2     76               // interior src tiles (76*16 = 1216)
#define FRAG_N  (2 * NCH * 64 * 8)   // 64512 u16 per A-frag table
#define EPB2    4000             // edges per block (125 blocks)
#define NBLK_P  NT1              // persistent blocks
#define BAR_STRIDE 32            // ints between arrival slots (128 B)
#define BAR_N   ((NBLK_P + 1) * BAR_STRIDE)

typedef float  f32x4 __attribute__((ext_vector_type(4)));
typedef short  s16x8 __attribute__((ext_vector_type(8)));
typedef unsigned long long u64;

__device__ __forceinline__ float bits_to_f32(unsigned u) {
    union { unsigned u; float f; } c; c.u = u; return c.f;
}
__device__ __forceinline__ unsigned f32_to_bits(float f) {
    union { float f; unsigned u; } c; c.f = f; return c.u;
}
__device__ __forceinline__ unsigned short f32_to_bf16(float f) {
    unsigned u = f32_to_bits(f);
    return (unsigned short)((u + 0x7FFFu + ((u >> 16) & 1u)) >> 16);  // RNE
}
__device__ __forceinline__ float bf16_to_f32(unsigned short s) {
    return bits_to_f32((unsigned)s << 16);
}

// ---- coherent (L2-bypassing) access helpers: relaxed agent atomics ----
__device__ __forceinline__ u64 ald64(const void* p) {
    return __hip_atomic_load((const u64*)p, __ATOMIC_RELAXED,
                             __HIP_MEMORY_SCOPE_AGENT);
}
__device__ __forceinline__ void ast64(void* p, u64 v) {
    __hip_atomic_store((u64*)p, v, __ATOMIC_RELAXED, __HIP_MEMORY_SCOPE_AGENT);
}
__device__ __forceinline__ unsigned short ald16(const unsigned short* p) {
    return __hip_atomic_load(p, __ATOMIC_RELAXED, __HIP_MEMORY_SCOPE_AGENT);
}
__device__ __forceinline__ void ast16(unsigned short* p, unsigned short v) {
    __hip_atomic_store(p, v, __ATOMIC_RELAXED, __HIP_MEMORY_SCOPE_AGENT);
}
__device__ __forceinline__ int ali32(const int* p) {
    return __hip_atomic_load(p, __ATOMIC_RELAXED, __HIP_MEMORY_SCOPE_AGENT);
}
__device__ __forceinline__ void asi32(int* p, int v) {
    __hip_atomic_store(p, v, __ATOMIC_RELAXED, __HIP_MEMORY_SCOPE_AGENT);
}
__device__ __forceinline__ void ast32(float* p, float v) {
    __hip_atomic_store(p, v, __ATOMIC_RELAXED, __HIP_MEMORY_SCOPE_AGENT);
}
// explicit system-coherent scalar ops for the barrier words
__device__ __forceinline__ int cohld(const int* p) {
    int v;
    asm volatile("global_load_dword %0, %1, off sc0 sc1\n\ts_waitcnt vmcnt(0)"
                 : "=v"(v) : "v"(p) : "memory");
    return v;
}
__device__ __forceinline__ void cohst(int* p, int v) {
    asm volatile("global_store_dword %0, %1, off sc0 sc1"
                 :: "v"(p), "v"(v) : "memory");
}

// A-fragment u16 index for element (k, b) of fx/err tables (m = b&15).
__device__ __forceinline__ int aposKB(int k, int b) {
    int c = k >> 5, q = (k >> 3) & 3, j = k & 7;
    int h = b >> 4, m = b & 15;
    return (((h * NCH + c) * 64) + q * 16 + m) * 8 + j;
}

// Fence-free device barrier (epoch-based, monotonic). Proven R15.
__device__ __forceinline__ void gbar(int* arr, int epoch, int bx, int tid) {
    asm volatile("s_waitcnt vmcnt(0) lgkmcnt(0)" ::: "memory");
    __syncthreads();
    if (bx == 0) {
        if (tid == 0) cohst(&arr[0], epoch);
        if (tid < NBLK_P) {
            while (cohld(&arr[tid * BAR_STRIDE]) < epoch)
                __builtin_amdgcn_s_sleep(2);
        }
        __syncthreads();
        if (tid == 0) cohst(&arr[NBLK_P * BAR_STRIDE], epoch);  // go
    } else {
        if (tid == 0) {
            cohst(&arr[bx * BAR_STRIDE], epoch);
            while (cohld(&arr[NBLK_P * BAR_STRIDE]) < epoch)
                __builtin_amdgcn_s_sleep(2);
        }
        __syncthreads();
    }
}

__global__ void k_zero_i32(int* a, int n) {
    int t = blockIdx.x * blockDim.x + threadIdx.x;
    if (t < n) a[t] = 0;
}

// ------------------------- THE kernel ------------------------------------
// 125 blocks x 512 threads. Phases A..E then the 5-step loop.
__global__ __launch_bounds__(512, 1) void k_all(
        const int* __restrict__ src, const int* __restrict__ dst,
        const float* __restrict__ wts, const float* __restrict__ vin,
        int* cnt_g, int* base_g, int* totals, unsigned* pk_g,
        uint4* WAbf4, unsigned short* WAdT,
        unsigned short* fxA, unsigned short* errA,
        float* v_cur, float* out, int* arr) {
    union LdsU {
        float acc[16][KP];                       // 129024 B (build)
        struct { uint4 A[NCH * 64]; uint4 B[NCH * 64]; } w;  // 129024 B (loop)
    };
    __shared__ LdsU U;
    __shared__ float red[2600];        // 10400 B
    __shared__ int sh_scan[128];
    __shared__ int ts[NT1 + 1];
    __shared__ int cur[NT1];
    __shared__ int cnt_l[NT1];

    const int bx = blockIdx.x, tid = threadIdx.x;
    int epoch = 0;

    // ---------------- phase A: init + histogram ----------------
    {
        int t = bx * 512 + tid;                  // exactly covers [0, NVB)
        if (t < 16 * 32) {                       // frag-table pad slots
            int k = 2000 + (t >> 5), bb = t & 31;
            ast16(&fxA[aposKB(k, bb)], 0);
            ast16(&errA[aposKB(k, bb)], 0);
        }
        if (t < N_INT * 2) {                     // WAdT pad rows (sc1!)
            u64* p = (u64*)(WAdT + (size_t)(t >> 1) * KP + 2000 + (t & 1) * 8);
            ast64(p, 0); ast64(p + 1, 0);
        }
        {
            float x = vin[t];
            int bb = t / N_V;
            int i = t - bb * N_V;
            ast32(&v_cur[(i << 5) + bb], x);
            ast16(&fxA[aposKB(i, bb)], f32_to_bf16(tanhf(x)));
            if (i < N_SENS) ast32(&out[t], x);
        }
        if (tid < NT1) cnt_l[tid] = 0;
        __syncthreads();
        int base = bx * EPB2;
        for (int e = base + tid; e < base + EPB2; e += 512)
            atomicAdd(&cnt_l[dst[e] >> 4], 1);
        __syncthreads();
        if (tid < NT1) asi32(&cnt_g[tid * 128 + bx], cnt_l[tid]);
    }
    ++epoch; gbar(arr, epoch, bx, tid);

    // ---------------- phase B: per-tile scan over blocks -------
    {
        int v = 0;
        if (tid < NT1) v = ali32(&cnt_g[bx * 128 + tid]);
        if (tid < 128) sh_scan[tid] = v;
        __syncthreads();
        for (int off = 1; off < 128; off <<= 1) {
            int x = (tid >= off && tid < 128) ? sh_scan[tid - off] : 0;
            __syncthreads();
            if (tid < 128) sh_scan[tid] += x;
            __syncthreads();
        }
        if (tid < NT1) asi32(&base_g[bx * 128 + tid], sh_scan[tid] - v);
        if (tid == NT1 - 1) asi32(&totals[bx], sh_scan[NT1 - 1]);
    }
    ++epoch; gbar(arr, epoch, bx, tid);

    // ---------------- phase C: tile_start + place --------------
    {
        int v = 0;
        if (tid < NT1) v = ali32(&totals[tid]);
        if (tid < 128) sh_scan[tid] = v;
        __syncthreads();
        for (int off = 1; off < 128; off <<= 1) {
            int x = (tid >= off && tid < 128) ? sh_scan[tid - off] : 0;
            __syncthreads();
            if (tid < 128) sh_scan[tid] += x;
            __syncthreads();
        }
        if (tid < NT1) ts[tid] = sh_scan[tid] - v;       // exclusive
        if (tid == NT1 - 1) ts[NT1] = sh_scan[NT1 - 1];  // total
        __syncthreads();
        if (tid < NT1) cur[tid] = ts[tid] + ali32(&base_g[tid * 128 + bx]);
        __syncthreads();
        int base = bx * EPB2;
        for (int e = base + tid; e < base + EPB2; e += 512) {
            int d = dst[e];
            unsigned pk = ((unsigned)f32_to_bf16(wts[e]) << 16)
                        | ((unsigned)(d & 15) << 11) | (unsigned)src[e];
            int p = atomicAdd(&cur[d >> 4], 1);
            asi32((int*)&pk_g[p], (int)pk);
        }
    }
    ++epoch; gbar(arr, epoch, bx, tid);

    // ---------------- phase D: build acc -> WAbf + WAdT --------
    {
        for (int i = tid; i < 16 * KP / 4; i += 512)
            ((float4*)&U.acc[0][0])[i] = make_float4(0.f, 0.f, 0.f, 0.f);
        __syncthreads();
        int beg = ts[bx], end = ts[bx + 1];
        for (int e = beg + tid; e < end; e += 512) {
            unsigned pk = (unsigned)ali32((const int*)&pk_g[e]);
            atomicAdd(&U.acc[(pk >> 11) & 15][pk & 0x7FFu],
                      bf16_to_f32((unsigned short)(pk >> 16)));
        }
        __syncthreads();
        // WAbf fragments: own tile, normal stores (same-block round trip)
        for (int i = tid; i < 16 * 252; i += 512) {
            int m = i / 252, g = i - m * 252;
            int c = g >> 2, q = g & 3;
            int col = g * 8;
            unsigned short r[8];
            #pragma unroll
            for (int j = 0; j < 8; ++j) r[j] = f32_to_bf16(U.acc[m][col + j]);
            WAbf4[((bx * NCH + c) * 64) + q * 16 + m] = *(const uint4*)r;
        }
        // WAdT columns (cross-block consumers): sc1 stores
        for (int i = tid; i < N_INT; i += 512) {
            union { unsigned short s[16]; u64 u[4]; } cc;
            #pragma unroll
            for (int m = 0; m < 16; ++m) cc.s[m] = f32_to_bf16(U.acc[m][N_SENS + i]);
            u64* p = (u64*)(WAdT + (size_t)i * KP + bx * 16);
            ast64(p, cc.u[0]); ast64(p + 1, cc.u[1]);
            ast64(p + 2, cc.u[2]); ast64(p + 3, cc.u[3]);
        }
    }
    ++epoch; gbar(arr, epoch, bx, tid);   // acc fully consumed; WAdT global

    // ---------------- phase E: stage W into LDS ----------------
    {
        const uint4* Wg = WAbf4 + (size_t)bx * (NCH * 64);
        for (int i = tid; i < NCH * 64; i += 512) U.w.A[i] = Wg[i];  // L2-hot
        if (bx < NT2) {
            for (int i = tid; i < NCH * 64; i += 512) {
                int c = i >> 6, ll = i & 63;
                int row = bx * 16 + (ll & 15);
                int k0 = c * 32 + (ll >> 4) * 8;
                const u64* p = (const u64*)(WAdT + (size_t)row * KP + k0);
                union { u64 u[2]; uint4 q; } cc;
                cc.u[0] = ald64(p); cc.u[1] = ald64(p + 1);
                U.w.B[i] = cc.q;
            }
        }
    }
    const int w = tid >> 6, l = tid & 63;
    const int h = w >> 2, w4 = w & 3;
    const int cbeg = w4 * 16;
    float* my = &red[h * 1300 + w4 * 325 + l * 5];
    __syncthreads();

    // ---------------- the 5-step loop (proven R15 structure) ----
    for (int t = 0; t < T_STEPS; ++t) {
        // phase 1: err (all 125 blocks)
        {
            const u64* ap = (const u64*)fxA
                          + ((size_t)h * (NCH * 64) + cbeg * 64 + l) * 2;
            u64 f0[16], f1[16];
            #pragma unroll
            for (int cc = 0; cc < 16; ++cc)
                if (cbeg + cc < NCH) {
                    f0[cc] = ald64(ap + cc * 128);
                    f1[cc] = ald64(ap + cc * 128 + 1);
                }
            __builtin_amdgcn_sched_barrier(0);
            f32x4 acc = {0.f, 0.f, 0.f, 0.f};
            #pragma unroll
            for (int cc = 0; cc < 16; ++cc)
                if (cbeg + cc < NCH) {
                    u64 d[2] = {f0[cc], f1[cc]};
                    uint4 bfrag = U.w.A[(cbeg + cc) * 64 + l];
                    acc = __builtin_amdgcn_mfma_f32_16x16x32_bf16(
                              *(s16x8*)d, *(s16x8*)&bfrag, acc, 0, 0, 0);
                }
            #pragma unroll
            for (int r = 0; r < 4; ++r) my[r] = acc[r];
            __syncthreads();
            if (w4 == 0) {
                float s[4];
                #pragma unroll
                for (int r = 0; r < 4; ++r)
                    s[r] = red[h * 1300 + l * 5 + r] + red[h * 1300 + 325 + l * 5 + r]
                         + red[h * 1300 + 650 + l * 5 + r] + red[h * 1300 + 975 + l * 5 + r];
                int i = bx * 16 + (l & 15);
                int q = l >> 4;
                int c2 = i >> 5, q2 = (i >> 3) & 3, j2 = i & 7;
                const float* vp = v_cur + (i << 5) + h * 16 + q * 4;
                union { u64 u[2]; float f[4]; } vu;
                vu.u[0] = ald64(vp);
                vu.u[1] = ald64(vp + 2);
                int base = ((h * NCH + c2) * 64 + q2 * 16) * 8 + j2;
                #pragma unroll
                for (int r = 0; r < 4; ++r)
                    ast16(&errA[base + (q * 4 + r) * 8],
                          f32_to_bf16(vu.f[r] - s[r]));
            }
        }
        ++epoch; gbar(arr, epoch, bx, tid);

        // phase 2: back + update (bx < 76)
        if (bx < NT2) {
            const u64* ap = (const u64*)errA
                          + ((size_t)h * (NCH * 64) + cbeg * 64 + l) * 2;
            u64 f0[16], f1[16];
            #pragma unroll
            for (int cc = 0; cc < 16; ++cc)
                if (cbeg + cc < NCH) {
                    f0[cc] = ald64(ap + cc * 128);
                    f1[cc] = ald64(ap + cc * 128 + 1);
                }
            __builtin_amdgcn_sched_barrier(0);
            f32x4 acc = {0.f, 0.f, 0.f, 0.f};
            #pragma unroll
            for (int cc = 0; cc < 16; ++cc)
                if (cbeg + cc < NCH) {
                    u64 d[2] = {f0[cc], f1[cc]};
                    uint4 bfrag = U.w.B[(cbeg + cc) * 64 + l];
                    acc = __builtin_amdgcn_mfma_f32_16x16x32_bf16(
                              *(s16x8*)d, *(s16x8*)&bfrag, acc, 0, 0, 0);
                }
            #pragma unroll
            for (int r = 0; r < 4; ++r) my[r] = acc[r];
            __syncthreads();
            if (w4 == 0) {
                float s[4];
                #pragma unroll
                for (int r = 0; r < 4; ++r)
                    s[r] = red[h * 1300 + l * 5 + r] + red[h * 1300 + 325 + l * 5 + r]
                         + red[h * 1300 + 650 + l * 5 + r] + red[h * 1300 + 975 + l * 5 + r];
                int j = N_SENS + bx * 16 + (l & 15);
                int q = l >> 4;
                int c2 = j >> 5, q2 = (j >> 3) & 3, j2 = j & 7;
                float* vp = v_cur + (j << 5) + h * 16 + q * 4;
                union { u64 u[2]; float f[4]; } vu;
                vu.u[0] = ald64(vp);
                vu.u[1] = ald64(vp + 2);
                int base = ((h * NCH + c2) * 64 + q2 * 16) * 8 + j2;
                #pragma unroll
                for (int r = 0; r < 4; ++r) {
                    float e0 = bf16_to_f32(ald16(&errA[base + (q * 4 + r) * 8]));
                    float fxv = tanhf(vu.f[r]);
                    float vn = vu.f[r] - LR_VAL * (e0 - (1.f - fxv * fxv) * s[r]);
                    vu.f[r] = vn;
                    ast16(&fxA[base + (q * 4 + r) * 8], f32_to_bf16(tanhf(vn)));
                }
                ast64(vp, vu.u[0]);
                ast64(vp + 2, vu.u[1]);
                if (t == T_STEPS - 1) {
                    #pragma unroll
                    for (int r = 0; r < 4; ++r) {
                        int b = h * 16 + q * 4 + r;
                        ast32(&out[b * N_V + j], vu.f[r]);
                    }
                }
            }
        }
        if (t < T_STEPS - 1) { ++epoch; gbar(arr, epoch, bx, tid); }
    }
}

// ------------------------- fallback path (R4 CSR, proven) ----------------

__global__ void k_hist(const int* __restrict__ src, const int* __restrict__ dst,
                       int* cnt_dst, int* cnt_src) {
    int e = blockIdx.x * blockDim.x + threadIdx.x;
    if (e < N_E) {
        atomicAdd(&cnt_dst[dst[e]], 1);
        atomicAdd(&cnt_src[src[e]], 1);
    }
}

__global__ __launch_bounds__(1024) void k_scan(int* cnt_a, int* rp_a,
                                               int* cnt_b, int* rp_b) {
    __shared__ int sh[1024];
    int t = threadIdx.x;
    for (int pass = 0; pass < 2; ++pass) {
        int* cnt = pass ? cnt_b : cnt_a;
        int* rp  = pass ? rp_b  : rp_a;
        int i0 = 2 * t, i1 = 2 * t + 1;
        int c0 = (i0 < N_V) ? cnt[i0] : 0;
        int c1 = (i1 < N_V) ? cnt[i1] : 0;
        __syncthreads();
        sh[t] = c0 + c1;
        __syncthreads();
        for (int off = 1; off < 1024; off <<= 1) {
            int v = (t >= off) ? sh[t - off] : 0;
            __syncthreads();
            sh[t] += v;
            __syncthreads();
        }
        int incl = sh[t];
        int e0 = incl - (c0 + c1);
        int e1 = e0 + c0;
        if (i0 <= N_V) rp[i0] = e0;
        if (i1 <= N_V) rp[i1] = e1;
        if (i0 < N_V) cnt[i0] = e0;
        if (i1 < N_V) cnt[i1] = e1;
    }
}

__global__ void k_scatter(const int* __restrict__ src, const int* __restrict__ dst,
                          const float* __restrict__ w,
                          int* cur_dst, int* cur_src,
                          unsigned* __restrict__ pk_dst, unsigned* __restrict__ pk_src) {
    int e = blockIdx.x * blockDim.x + threadIdx.x;
    if (e < N_E) {
        int s = src[e], d = dst[e];
        unsigned wbits = (unsigned)f32_to_bf16(w[e]);
        int p = atomicAdd(&cur_dst[d], 1);
        pk_dst[p] = (wbits << 16) | (unsigned)s;
        int q = atomicAdd(&cur_src[s], 1);
        pk_src[q] = (wbits << 16) | (unsigned)d;
    }
}

__global__ void k_cast_in(const float* __restrict__ vin, float* __restrict__ v) {
    int t = blockIdx.x * blockDim.x + threadIdx.x;
    if (t < NVB) {
        int i = t >> 5, b = t & 31;
        v[t] = vin[b * N_V + i];
    }
}

__global__ void k_fx_csr(const float* __restrict__ v, unsigned short* __restrict__ fx) {
    int t = blockIdx.x * blockDim.x + threadIdx.x;
    if (t < NVB) {
        int i = t >> 5, b = t & 31;
        int h = b >> 4, b16 = b & 15;
        fx[h * NVH + i * 16 + b16] = f32_to_bf16(tanhf(v[t]));
    }
}

__global__ __launch_bounds__(256) void k_pred_err(
        const float* __restrict__ v, const unsigned short* __restrict__ fx,
        const int* __restrict__ rp, const unsigned* __restrict__ pk,
        unsigned short* __restrict__ err) {
    __shared__ unsigned short tab[NVH];
    int h  = blockIdx.x / 250;
    int vg = blockIdx.x % 250;
    {
        const uint4* g = (const uint4*)(fx + h * NVH);
        uint4* l = (uint4*)tab;
        for (int i = threadIdx.x; i < NVH / 8; i += 256) l[i] = g[i];
    }
    __syncthreads();
    int wave = threadIdx.x >> 6;
    int lane = threadIdx.x & 63;
    int b16 = lane & 15, epar = lane >> 4;
    for (int k = 0; k < 2; ++k) {
        int vid = vg * 8 + wave * 2 + k;
        int beg = rp[vid], end = rp[vid + 1];
        float sum = 0.f;
        for (int e = beg + epar; e < end; e += 4) {
            unsigned p = pk[e];
            float w = bits_to_f32(p & 0xFFFF0000u);
            int nb = (int)(p & 0xFFFFu);
            sum += w * bf16_to_f32(tab[nb * 16 + b16]);
        }
        sum += __shfl_xor(sum, 16, 64);
        sum += __shfl_xor(sum, 32, 64);
        if (epar == 0) {
            float vo = v[(vid << 5) + h * 16 + b16];
            err[h * NVH + vid * 16 + b16] = f32_to_bf16(vo - sum);
        }
    }
}

__global__ __launch_bounds__(256) void k_back_upd(
        const unsigned short* __restrict__ fx, const unsigned short* __restrict__ err,
        const int* __restrict__ rp, const unsigned* __restrict__ pk,
        float* __restrict__ v) {
    __shared__ unsigned short tab[NVH];
    int h  = blockIdx.x / 152;
    int vg = blockIdx.x % 152;
    {
        const uint4* g = (const uint4*)(err + h * NVH);
        uint4* l = (uint4*)tab;
        for (int i = threadIdx.x; i < NVH / 8; i += 256) l[i] = g[i];
    }
    __syncthreads();
    int wave = threadIdx.x >> 6;
    int lane = threadIdx.x & 63;
    int b16 = lane & 15, epar = lane >> 4;
    for (int k = 0; k < 2; ++k) {
        int vid = N_SENS + vg * 8 + wave * 2 + k;
        if (vid >= N_V) continue;
        int beg = rp[vid], end = rp[vid + 1];
        float sum = 0.f;
        for (int e = beg + epar; e < end; e += 4) {
            unsigned p = pk[e];
            float w = bits_to_f32(p & 0xFFFF0000u);
            int nb = (int)(p & 0xFFFFu);
            sum += w * bf16_to_f32(tab[nb * 16 + b16]);
        }
        sum += __shfl_xor(sum, 16, 64);
        sum += __shfl_xor(sum, 32, 64);
        if (epar == 0) {
            float e0  = bf16_to_f32(tab[vid * 16 + b16]);
            float fxv = bf16_to_f32(fx[h * NVH + vid * 16 + b16]);
            float dv = e0 - (1.f - fxv * fxv) * sum;
            v[(vid << 5) + h * 16 + b16] -= LR_VAL * dv;
        }
    }
}

__global__ void k_out_fb(const float* __restrict__ v, float* __restrict__ out) {
    int t = blockIdx.x * blockDim.x + threadIdx.x;
    if (t < NVB) {
        int b = t / N_V;
        int i = t - b * N_V;
        out[t] = v[(i << 5) + b];
    }
}

// ------------------------- host -----------------------------------------

extern "C" void kernel_launch(void* const* d_in, const int* in_sizes, int n_in,
                              void* d_out, int out_size, void* d_ws, size_t ws_size,
                              hipStream_t stream) {
    const float* vals = (const float*)d_in[0];
    const float* wts  = (const float*)d_in[1];
    const int* ei = (const int*)d_in[2];
    const int* src = ei;
    const int* dst = ei + N_E;
    float* out = (float*)d_out;

    const int EB = (N_E + 255) / 256;

    // ws layout: pk_g | cnt_g | base_g | totals | WAdT | WAbf | fxA | errA
    //            | v_cur | bar   (~20.4 MB)
    const size_t WABF_T = (size_t)NT1 * NCH * 64;        // uint4 count
    const size_t WADT_N = (size_t)N_INT * KP;            // u16 count
    const size_t need = (size_t)N_E * 4 + 2 * NT1 * 128 * 4 + 512
                      + WADT_N * 2 + WABF_T * 16
                      + 2 * (size_t)FRAG_N * 2 + NVB * 4
                      + (size_t)BAR_N * 4 + 256;

    if (ws_size >= need) {
        unsigned* pk_g = (unsigned*)d_ws;
        int* cnt_g  = (int*)(pk_g + N_E);
        int* base_g = cnt_g + NT1 * 128;
        int* totals = base_g + NT1 * 128;
        unsigned short* WAdT = (unsigned short*)(totals + 128);
        uint4* WAbf4 = (uint4*)(WAdT + WADT_N);
        unsigned short* fxA  = (unsigned short*)(WAbf4 + WABF_T);
        unsigned short* errA = fxA + FRAG_N;
        float* v_cur = (float*)(errA + FRAG_N);
        int* bar_arr = (int*)(v_cur + NVB);   // dedicated region

        k_zero_i32<<<16, 256, 0, stream>>>(bar_arr, BAR_N);
        k_all<<<NBLK_P, 512, 0, stream>>>(src, dst, wts, vals,
                                          cnt_g, base_g, totals, pk_g,
                                          WAbf4, WAdT, fxA, errA,
                                          v_cur, out, bar_arr);
    } else {
        float* v_cur = (float*)d_ws;
        unsigned short* fx_g  = (unsigned short*)(v_cur + NVB);
        unsigned short* err_g = fx_g + NVB;
        int* rp_dst  = (int*)(err_g + NVB);
        int* rp_src  = rp_dst + 2048;
        int* cur_dst = rp_src + 2048;
        int* cur_src = cur_dst + 2048;
        unsigned* pk_dst = (unsigned*)(cur_src + 2048);
        unsigned* pk_src = pk_dst + N_E;

        k_zero_i32<<<16, 256, 0, stream>>>(cur_dst, 4096);
        k_hist<<<EB, 256, 0, stream>>>(src, dst, cur_dst, cur_src);
        k_scan<<<1, 1024, 0, stream>>>(cur_dst, rp_dst, cur_src, rp_src);
        k_scatter<<<EB, 256, 0, stream>>>(src, dst, wts, cur_dst, cur_src,
                                          pk_dst, pk_src);
        k_cast_in<<<250, 256, 0, stream>>>(vals, v_cur);
        for (int t = 0; t < T_STEPS; ++t) {
            k_fx_csr<<<250, 256, 0, stream>>>(v_cur, fx_g);
            k_pred_err<<<500, 256, 0, stream>>>(v_cur, fx_g, rp_dst, pk_dst, err_g);
            k_back_upd<<<304, 256, 0, stream>>>(fx_g, err_g, rp_src, pk_src, v_cur);
        }
        k_out_fb<<<250, 256, 0, stream>>>(v_cur, out);
    }
}

// Round 7
// 149.538 us; speedup vs baseline: 1.1356x; 1.1356x over previous
//
#include <hip/hip_runtime.h>
#include <hip/hip_bf16.h>

// PCGraphConv: iterative predictive-coding message passing.
// N_V=2000, N_SENS=784, N_E=500000, BATCH=32, T=5, lr=0.1.
// R19: R17 chain (proven, 153.6us total) + 250-block k_loop.
//  R18 post-mortem: full fusion regressed (prep on half the CUs, sc1
//  write-through 49MB). Reverted to R17's 4-kernel chain.
//  k_loop change: block = (tile, batch-half) -> 250 blocks x 512 thr.
//  Same total LLC bytes for A-frag streaming but 2x CUs issuing (the
//  loop phases are LLC-BW-bound: 129MB/10 phases ~ 3.5TB/s at 125 CUs).
//  8 waves = 8 K-eighths (8-MFMA chains), reduce over 8 partials.
// Fallback: proven R4 CSR path if ws too small.

#define N_V     2000
#define N_SENS  784
#define N_INT   (N_V - N_SENS)   // 1216
#define N_E     500000
#define T_STEPS 5
#define LR_VAL  0.1f
#define NVB     (N_V * 32)       // 64000
#define NVH     (N_V * 16)       // 32000
#define KP      2016             // padded K (63 chunks of 32)
#define NCH     63               // K chunks
#define NT1     125              // dst tiles (125*16 = 2000)
#define NT2     76               // interior src tiles (76*16 = 1216)
#define FRAG_N  (2 * NCH * 64 * 8)   // 64512 u16 per A-frag table
#define NBLK    250              // sort blocks
#define EPB     2000             // edges per sort block
#define NBLK_P  250              // persistent blocks (tile x batch-half)
#define BAR_STRIDE 32            // ints between arrival slots (128 B)
#define BAR_N   ((NBLK_P + 1) * BAR_STRIDE)

typedef float  f32x4 __attribute__((ext_vector_type(4)));
typedef short  s16x8 __attribute__((ext_vector_type(8)));
typedef unsigned long long u64;

__device__ __forceinline__ float bits_to_f32(unsigned u) {
    union { unsigned u; float f; } c; c.u = u; return c.f;
}
__device__ __forceinline__ unsigned f32_to_bits(float f) {
    union { float f; unsigned u; } c; c.f = f; return c.u;
}
__device__ __forceinline__ unsigned short f32_to_bf16(float f) {
    unsigned u = f32_to_bits(f);
    return (unsigned short)((u + 0x7FFFu + ((u >> 16) & 1u)) >> 16);  // RNE
}
__device__ __forceinline__ float bf16_to_f32(unsigned short s) {
    return bits_to_f32((unsigned)s << 16);
}

// ---- coherent (L2-bypassing) access helpers: relaxed agent atomics ----
__device__ __forceinline__ u64 ald64(const void* p) {
    return __hip_atomic_load((const u64*)p, __ATOMIC_RELAXED,
                             __HIP_MEMORY_SCOPE_AGENT);
}
__device__ __forceinline__ void ast64(void* p, u64 v) {
    __hip_atomic_store((u64*)p, v, __ATOMIC_RELAXED, __HIP_MEMORY_SCOPE_AGENT);
}
__device__ __forceinline__ unsigned short ald16(const unsigned short* p) {
    return __hip_atomic_load(p, __ATOMIC_RELAXED, __HIP_MEMORY_SCOPE_AGENT);
}
__device__ __forceinline__ void ast16(unsigned short* p, unsigned short v) {
    __hip_atomic_store(p, v, __ATOMIC_RELAXED, __HIP_MEMORY_SCOPE_AGENT);
}
// explicit system-coherent scalar ops for the barrier words
__device__ __forceinline__ int cohld(const int* p) {
    int v;
    asm volatile("global_load_dword %0, %1, off sc0 sc1\n\ts_waitcnt vmcnt(0)"
                 : "=v"(v) : "v"(p) : "memory");
    return v;
}
__device__ __forceinline__ void cohst(int* p, int v) {
    asm volatile("global_store_dword %0, %1, off sc0 sc1"
                 :: "v"(p), "v"(v) : "memory");
}

// A-fragment u16 index for element (k, b) of fx/err tables (m = b&15).
__device__ __forceinline__ int aposKB(int k, int b) {
    int c = k >> 5, q = (k >> 3) & 3, j = k & 7;
    int h = b >> 4, m = b & 15;
    return (((h * NCH + c) * 64) + q * 16 + m) * 8 + j;
}

// ------------------------- dense/MFMA path -------------------------------

// histogram edges by dst-tile (cnt_g layout [tile][block]) + merged init:
// v_cur/fxA/out from vin; zero frag pads, WAdT pad rows, barrier slots.
__global__ __launch_bounds__(256) void k_cnt(const int* __restrict__ dst,
                                             int* __restrict__ cnt_g,
                                             unsigned short* __restrict__ fxA,
                                             unsigned short* __restrict__ errA,
                                             const float* __restrict__ vin,
                                             float* __restrict__ v,
                                             float* __restrict__ out,
                                             unsigned short* __restrict__ WAdT,
                                             int* __restrict__ bar) {
    __shared__ int cnt[NT1];
    int b = blockIdx.x;
    int t = b * 256 + threadIdx.x;
    {   // zero pad slots k in [2000,2016) of both frag tables
        if (t < 16 * 32) {
            int k = 2000 + (t >> 5), bb = t & 31;
            fxA[aposKB(k, bb)] = 0;
            errA[aposKB(k, bb)] = 0;
        }
        // zero WAdT pad rows k in [2000,2016) for all 1216 columns
        if (t < N_INT * 2) {
            uint4 z = {0u, 0u, 0u, 0u};
            *(uint4*)(WAdT + (size_t)(t >> 1) * KP + 2000 + (t & 1) * 8) = z;
        }
        // zero barrier slots + go word
        if (t < BAR_N) bar[t] = 0;
    }
    // merged k_init: coalesced read of vin, scattered L2-hot writes
    if (t < NVB) {
        float x = vin[t];
        int bb = t / N_V;
        int i = t - bb * N_V;
        v[(i << 5) + bb] = x;
        fxA[aposKB(i, bb)] = f32_to_bf16(tanhf(x));
        if (i < N_SENS) out[t] = x;
    }
    for (int i = threadIdx.x; i < NT1; i += 256) cnt[i] = 0;
    __syncthreads();
    int base = b * EPB;
    for (int e = base + threadIdx.x; e < base + EPB; e += 256)
        atomicAdd(&cnt[dst[e] >> 4], 1);
    __syncthreads();
    for (int tt = threadIdx.x; tt < NT1; tt += 256)
        cnt_g[tt * 256 + b] = cnt[tt];
}

// per-tile exclusive scan over blocks; totals[t] = tile edge count
__global__ __launch_bounds__(256) void k_scan_a(const int* __restrict__ cnt_g,
                                                int* __restrict__ base_g,
                                                int* __restrict__ totals) {
    __shared__ int sh[256];
    int t = blockIdx.x, tid = threadIdx.x;
    int v = (tid < NBLK) ? cnt_g[t * 256 + tid] : 0;
    sh[tid] = v;
    __syncthreads();
    for (int off = 1; off < 256; off <<= 1) {
        int x = (tid >= off) ? sh[tid - off] : 0;
        __syncthreads();
        sh[tid] += x;
        __syncthreads();
    }
    if (tid < NBLK) base_g[t * 256 + tid] = sh[tid] - v;   // exclusive
    if (tid == 255) totals[t] = sh[255];
}

// place edges into sorted order: pk = (bf16w<<16)|(row4<<11)|src
// tile_start computed locally from totals (k_scan_b eliminated).
__global__ __launch_bounds__(256) void k_place(
        const int* __restrict__ src, const int* __restrict__ dst,
        const float* __restrict__ w, const int* __restrict__ base_g,
        const int* __restrict__ totals, unsigned* __restrict__ pk_g) {
    __shared__ int cur[NT1];
    __shared__ int ts[NT1];
    int b = blockIdx.x;
    if (threadIdx.x == 0) {
        int a = 0;
        for (int t = 0; t < NT1; ++t) { ts[t] = a; a += totals[t]; }
    }
    __syncthreads();
    for (int t = threadIdx.x; t < NT1; t += 256)
        cur[t] = ts[t] + base_g[t * 256 + b];
    __syncthreads();
    int base = b * EPB;
    for (int e = base + threadIdx.x; e < base + EPB; e += 256) {
        int d = dst[e];
        unsigned pk = ((unsigned)f32_to_bf16(w[e]) << 16)
                    | ((unsigned)(d & 15) << 11) | (unsigned)src[e];
        int p = atomicAdd(&cur[d >> 4], 1);
        pk_g[p] = pk;
    }
}

// build WAbf fragments + TRANSPOSED dense bf16 WAdT from sorted edges.
// One block per tile: acc[16][KP] = 129 KB LDS; tile edges read ONCE.
__global__ __launch_bounds__(256) void k_build(
        const unsigned* __restrict__ pk_g, const int* __restrict__ totals,
        uint4* __restrict__ WAbf4, unsigned short* __restrict__ WAdT) {
    __shared__ float acc[16][KP];   // 129 KB
    __shared__ int ts[NT1 + 1];
    int tile = blockIdx.x;
    for (int i = threadIdx.x; i < 16 * KP / 4; i += 256)
        ((float4*)&acc[0][0])[i] = make_float4(0.f, 0.f, 0.f, 0.f);
    if (threadIdx.x == 0) {
        int a = 0;
        for (int t = 0; t < NT1; ++t) { ts[t] = a; a += totals[t]; }
        ts[NT1] = a;
    }
    __syncthreads();
    int beg = ts[tile], end = ts[tile + 1];
    for (int e = beg + threadIdx.x; e < end; e += 256) {
        unsigned pk = pk_g[e];
        int row = (int)((pk >> 11) & 15u);
        atomicAdd(&acc[row][pk & 0x7FFu], bf16_to_f32((unsigned short)(pk >> 16)));
    }
    __syncthreads();
    // emit WAbf fragments (all 16 rows)
    for (int i = threadIdx.x; i < 16 * 252; i += 256) {
        int m = i / 252, g = i - m * 252;
        int c = g >> 2, q = g & 3;
        int col = g * 8;
        unsigned short r[8];
        #pragma unroll
        for (int j = 0; j < 8; ++j) r[j] = f32_to_bf16(acc[m][col + j]);
        WAbf4[((tile * NCH + c) * 64) + q * 16 + m] = *(const uint4*)r;
    }
    // emit WAdT columns j in [784,2000): 16 bf16 (this tile's dst rows)
    for (int i = threadIdx.x; i < N_INT; i += 256) {
        int j = N_SENS + i;
        unsigned short r[16];
        #pragma unroll
        for (int m = 0; m < 16; ++m) r[m] = f32_to_bf16(acc[m][j]);
        uint4* p = (uint4*)(WAdT + (size_t)i * KP + tile * 16);
        p[0] = *(const uint4*)r;
        p[1] = *(const uint4*)(r + 8);
    }
}

// Fence-free device barrier (epoch-based, monotonic). Proven R15.
__device__ __forceinline__ void gbar(int* arr, int epoch, int bx, int tid) {
    asm volatile("s_waitcnt vmcnt(0) lgkmcnt(0)" ::: "memory");
    __syncthreads();
    if (bx == 0) {
        if (tid == 0) cohst(&arr[0], epoch);
        if (tid < NBLK_P) {
            while (cohld(&arr[tid * BAR_STRIDE]) < epoch)
                __builtin_amdgcn_s_sleep(2);
        }
        __syncthreads();
        if (tid == 0) cohst(&arr[NBLK_P * BAR_STRIDE], epoch);  // go
    } else {
        if (tid == 0) {
            cohst(&arr[bx * BAR_STRIDE], epoch);
            while (cohld(&arr[NBLK_P * BAR_STRIDE]) < epoch)
                __builtin_amdgcn_s_sleep(2);
        }
        __syncthreads();
    }
}

// persistent T-loop. 250 blocks x 512 threads: tile = bx>>1, half = bx&1.
// phase1 (all 250):  err = v - fx.WA^T for (tile, half).
// phase2 (bx < 152): back = err.WB^T + v update for (src tile, half).
// 8 waves = 8 K-eighths (8 chunks each); reduce over 8 partials.
__global__ __launch_bounds__(512, 1) void k_loop(
        const uint4* __restrict__ WAbf4, const unsigned short* __restrict__ WAdT,
        unsigned short* fxA, unsigned short* errA,
        float* v_cur, float* __restrict__ out, int* arr) {
    __shared__ uint4 WldsA[NCH * 64];   // 64512 B
    __shared__ uint4 WldsB[NCH * 64];   // 64512 B
    __shared__ float red[2600];         // 10400 B
    const int bx = blockIdx.x, tid = threadIdx.x;
    const int tile = bx >> 1, h = bx & 1;
    {
        const uint4* Wg = WAbf4 + (size_t)tile * (NCH * 64);
        for (int i = tid; i < NCH * 64; i += 512) WldsA[i] = Wg[i];
        if (bx < 2 * NT2) {
            for (int i = tid; i < NCH * 64; i += 512) {
                int c = i >> 6, ll = i & 63;
                int row = tile * 16 + (ll & 15);
                int k0 = c * 32 + (ll >> 4) * 8;
                WldsB[i] = *(const uint4*)(WAdT + (size_t)row * KP + k0);
            }
        }
    }
    const int w = tid >> 6, l = tid & 63;
    const int cbeg = w * 8;                 // 8 chunks per wave
    float* my = &red[w * 325 + l * 5];
    int epoch = 0;
    __syncthreads();

    for (int t = 0; t < T_STEPS; ++t) {
        // ---------------- phase 1: err (all 250 blocks) ----------------
        {
            const u64* ap = (const u64*)fxA
                          + ((size_t)h * (NCH * 64) + cbeg * 64 + l) * 2;
            u64 f0[8], f1[8];
            #pragma unroll
            for (int cc = 0; cc < 8; ++cc)
                if (cbeg + cc < NCH) {
                    f0[cc] = ald64(ap + cc * 128);
                    f1[cc] = ald64(ap + cc * 128 + 1);
                }
            __builtin_amdgcn_sched_barrier(0);
            f32x4 acc = {0.f, 0.f, 0.f, 0.f};
            #pragma unroll
            for (int cc = 0; cc < 8; ++cc)
                if (cbeg + cc < NCH) {
                    u64 d[2] = {f0[cc], f1[cc]};
                    uint4 bfrag = WldsA[(cbeg + cc) * 64 + l];
                    acc = __builtin_amdgcn_mfma_f32_16x16x32_bf16(
                              *(s16x8*)d, *(s16x8*)&bfrag, acc, 0, 0, 0);
                }
            #pragma unroll
            for (int r = 0; r < 4; ++r) my[r] = acc[r];
            __syncthreads();
            if (w == 0) {
                float s[4];
                #pragma unroll
                for (int r = 0; r < 4; ++r) {
                    float sum = 0.f;
                    #pragma unroll
                    for (int ww = 0; ww < 8; ++ww)
                        sum += red[ww * 325 + l * 5 + r];
                    s[r] = sum;
                }
                int i = tile * 16 + (l & 15);
                int q = l >> 4;
                int c2 = i >> 5, q2 = (i >> 3) & 3, j2 = i & 7;
                const float* vp = v_cur + (i << 5) + h * 16 + q * 4;
                union { u64 u[2]; float f[4]; } vu;
                vu.u[0] = ald64(vp);
                vu.u[1] = ald64(vp + 2);
                int base = ((h * NCH + c2) * 64 + q2 * 16) * 8 + j2;
                #pragma unroll
                for (int r = 0; r < 4; ++r)
                    ast16(&errA[base + (q * 4 + r) * 8],
                          f32_to_bf16(vu.f[r] - s[r]));
            }
        }
        ++epoch; gbar(arr, epoch, bx, tid);

        // ---------------- phase 2: back + update (bx < 152) ------------
        if (bx < 2 * NT2) {
            const u64* ap = (const u64*)errA
                          + ((size_t)h * (NCH * 64) + cbeg * 64 + l) * 2;
            u64 f0[8], f1[8];
            #pragma unroll
            for (int cc = 0; cc < 8; ++cc)
                if (cbeg + cc < NCH) {
                    f0[cc] = ald64(ap + cc * 128);
                    f1[cc] = ald64(ap + cc * 128 + 1);
                }
            __builtin_amdgcn_sched_barrier(0);
            f32x4 acc = {0.f, 0.f, 0.f, 0.f};
            #pragma unroll
            for (int cc = 0; cc < 8; ++cc)
                if (cbeg + cc < NCH) {
                    u64 d[2] = {f0[cc], f1[cc]};
                    uint4 bfrag = WldsB[(cbeg + cc) * 64 + l];
                    acc = __builtin_amdgcn_mfma_f32_16x16x32_bf16(
                              *(s16x8*)d, *(s16x8*)&bfrag, acc, 0, 0, 0);
                }
            #pragma unroll
            for (int r = 0; r < 4; ++r) my[r] = acc[r];
            __syncthreads();
            if (w == 0) {
                float s[4];
                #pragma unroll
                for (int r = 0; r < 4; ++r) {
                    float sum = 0.f;
                    #pragma unroll
                    for (int ww = 0; ww < 8; ++ww)
                        sum += red[ww * 325 + l * 5 + r];
                    s[r] = sum;
                }
                int j = N_SENS + tile * 16 + (l & 15);
                int q = l >> 4;
                int c2 = j >> 5, q2 = (j >> 3) & 3, j2 = j & 7;
                float* vp = v_cur + (j << 5) + h * 16 + q * 4;
                union { u64 u[2]; float f[4]; } vu;
                vu.u[0] = ald64(vp);
                vu.u[1] = ald64(vp + 2);
                int base = ((h * NCH + c2) * 64 + q2 * 16) * 8 + j2;
                #pragma unroll
                for (int r = 0; r < 4; ++r) {
                    float e0 = bf16_to_f32(ald16(&errA[base + (q * 4 + r) * 8]));
                    float fxv = tanhf(vu.f[r]);
                    float vn = vu.f[r] - LR_VAL * (e0 - (1.f - fxv * fxv) * s[r]);
                    vu.f[r] = vn;
                    ast16(&fxA[base + (q * 4 + r) * 8], f32_to_bf16(tanhf(vn)));
                }
                ast64(vp, vu.u[0]);
                ast64(vp + 2, vu.u[1]);
                if (t == T_STEPS - 1) {
                    #pragma unroll
                    for (int r = 0; r < 4; ++r) {
                        int b = h * 16 + q * 4 + r;
                        out[b * N_V + j] = vu.f[r];
                    }
                }
            }
        }
        if (t < T_STEPS - 1) { ++epoch; gbar(arr, epoch, bx, tid); }
    }
}

// ------------------------- fallback path (R4 CSR, proven) ----------------

__global__ void k_zero_i32(int* a, int n) {
    int t = blockIdx.x * blockDim.x + threadIdx.x;
    if (t < n) a[t] = 0;
}

__global__ void k_hist(const int* __restrict__ src, const int* __restrict__ dst,
                       int* cnt_dst, int* cnt_src) {
    int e = blockIdx.x * blockDim.x + threadIdx.x;
    if (e < N_E) {
        atomicAdd(&cnt_dst[dst[e]], 1);
        atomicAdd(&cnt_src[src[e]], 1);
    }
}

__global__ __launch_bounds__(1024) void k_scan(int* cnt_a, int* rp_a,
                                               int* cnt_b, int* rp_b) {
    __shared__ int sh[1024];
    int t = threadIdx.x;
    for (int pass = 0; pass < 2; ++pass) {
        int* cnt = pass ? cnt_b : cnt_a;
        int* rp  = pass ? rp_b  : rp_a;
        int i0 = 2 * t, i1 = 2 * t + 1;
        int c0 = (i0 < N_V) ? cnt[i0] : 0;
        int c1 = (i1 < N_V) ? cnt[i1] : 0;
        __syncthreads();
        sh[t] = c0 + c1;
        __syncthreads();
        for (int off = 1; off < 1024; off <<= 1) {
            int v = (t >= off) ? sh[t - off] : 0;
            __syncthreads();
            sh[t] += v;
            __syncthreads();
        }
        int incl = sh[t];
        int e0 = incl - (c0 + c1);
        int e1 = e0 + c0;
        if (i0 <= N_V) rp[i0] = e0;
        if (i1 <= N_V) rp[i1] = e1;
        if (i0 < N_V) cnt[i0] = e0;
        if (i1 < N_V) cnt[i1] = e1;
    }
}

__global__ void k_scatter(const int* __restrict__ src, const int* __restrict__ dst,
                          const float* __restrict__ w,
                          int* cur_dst, int* cur_src,
                          unsigned* __restrict__ pk_dst, unsigned* __restrict__ pk_src) {
    int e = blockIdx.x * blockDim.x + threadIdx.x;
    if (e < N_E) {
        int s = src[e], d = dst[e];
        unsigned wbits = (unsigned)f32_to_bf16(w[e]);
        int p = atomicAdd(&cur_dst[d], 1);
        pk_dst[p] = (wbits << 16) | (unsigned)s;
        int q = atomicAdd(&cur_src[s], 1);
        pk_src[q] = (wbits << 16) | (unsigned)d;
    }
}

__global__ void k_cast_in(const float* __restrict__ vin, float* __restrict__ v) {
    int t = blockIdx.x * blockDim.x + threadIdx.x;
    if (t < NVB) {
        int i = t >> 5, b = t & 31;
        v[t] = vin[b * N_V + i];
    }
}

__global__ void k_fx_csr(const float* __restrict__ v, unsigned short* __restrict__ fx) {
    int t = blockIdx.x * blockDim.x + threadIdx.x;
    if (t < NVB) {
        int i = t >> 5, b = t & 31;
        int h = b >> 4, b16 = b & 15;
        fx[h * NVH + i * 16 + b16] = f32_to_bf16(tanhf(v[t]));
    }
}

__global__ __launch_bounds__(256) void k_pred_err(
        const float* __restrict__ v, const unsigned short* __restrict__ fx,
        const int* __restrict__ rp, const unsigned* __restrict__ pk,
        unsigned short* __restrict__ err) {
    __shared__ unsigned short tab[NVH];
    int h  = blockIdx.x / 250;
    int vg = blockIdx.x % 250;
    {
        const uint4* g = (const uint4*)(fx + h * NVH);
        uint4* l = (uint4*)tab;
        for (int i = threadIdx.x; i < NVH / 8; i += 256) l[i] = g[i];
    }
    __syncthreads();
    int wave = threadIdx.x >> 6;
    int lane = threadIdx.x & 63;
    int b16 = lane & 15, epar = lane >> 4;
    for (int k = 0; k < 2; ++k) {
        int vid = vg * 8 + wave * 2 + k;
        int beg = rp[vid], end = rp[vid + 1];
        float sum = 0.f;
        for (int e = beg + epar; e < end; e += 4) {
            unsigned p = pk[e];
            float w = bits_to_f32(p & 0xFFFF0000u);
            int nb = (int)(p & 0xFFFFu);
            sum += w * bf16_to_f32(tab[nb * 16 + b16]);
        }
        sum += __shfl_xor(sum, 16, 64);
        sum += __shfl_xor(sum, 32, 64);
        if (epar == 0) {
            float vo = v[(vid << 5) + h * 16 + b16];
            err[h * NVH + vid * 16 + b16] = f32_to_bf16(vo - sum);
        }
    }
}

__global__ __launch_bounds__(256) void k_back_upd(
        const unsigned short* __restrict__ fx, const unsigned short* __restrict__ err,
        const int* __restrict__ rp, const unsigned* __restrict__ pk,
        float* __restrict__ v) {
    __shared__ unsigned short tab[NVH];
    int h  = blockIdx.x / 152;
    int vg = blockIdx.x % 152;
    {
        const uint4* g = (const uint4*)(err + h * NVH);
        uint4* l = (uint4*)tab;
        for (int i = threadIdx.x; i < NVH / 8; i += 256) l[i] = g[i];
    }
    __syncthreads();
    int wave = threadIdx.x >> 6;
    int lane = threadIdx.x & 63;
    int b16 = lane & 15, epar = lane >> 4;
    for (int k = 0; k < 2; ++k) {
        int vid = N_SENS + vg * 8 + wave * 2 + k;
        if (vid >= N_V) continue;
        int beg = rp[vid], end = rp[vid + 1];
        float sum = 0.f;
        for (int e = beg + epar; e < end; e += 4) {
            unsigned p = pk[e];
            float w = bits_to_f32(p & 0xFFFF0000u);
            int nb = (int)(p & 0xFFFFu);
            sum += w * bf16_to_f32(tab[nb * 16 + b16]);
        }
        sum += __shfl_xor(sum, 16, 64);
        sum += __shfl_xor(sum, 32, 64);
        if (epar == 0) {
            float e0  = bf16_to_f32(tab[vid * 16 + b16]);
            float fxv = bf16_to_f32(fx[h * NVH + vid * 16 + b16]);
            float dv = e0 - (1.f - fxv * fxv) * sum;
            v[(vid << 5) + h * 16 + b16] -= LR_VAL * dv;
        }
    }
}

__global__ void k_out_fb(const float* __restrict__ v, float* __restrict__ out) {
    int t = blockIdx.x * blockDim.x + threadIdx.x;
    if (t < NVB) {
        int b = t / N_V;
        int i = t - b * N_V;
        out[t] = v[(i << 5) + b];
    }
}

// ------------------------- host -----------------------------------------

extern "C" void kernel_launch(void* const* d_in, const int* in_sizes, int n_in,
                              void* d_out, int out_size, void* d_ws, size_t ws_size,
                              hipStream_t stream) {
    const float* vals = (const float*)d_in[0];
    const float* wts  = (const float*)d_in[1];
    const int* ei = (const int*)d_in[2];
    const int* src = ei;
    const int* dst = ei + N_E;
    float* out = (float*)d_out;

    const int EB = (N_E + 255) / 256;

    // ws layout: pk_g | cnt_g | base_g | totals | WAdT | WAbf | fxA | errA
    //            | v_cur | bar   (~20.5 MB)
    const size_t WABF_T = (size_t)NT1 * NCH * 64;        // uint4 count
    const size_t WADT_N = (size_t)N_INT * KP;            // u16 count
    const size_t need = (size_t)N_E * 4 + 2 * NT1 * 256 * 4 + 512
                      + WADT_N * 2 + WABF_T * 16
                      + 2 * (size_t)FRAG_N * 2 + NVB * 4
                      + (size_t)BAR_N * 4 + 256;

    if (ws_size >= need) {
        unsigned* pk_g = (unsigned*)d_ws;
        int* cnt_g  = (int*)(pk_g + N_E);
        int* base_g = cnt_g + NT1 * 256;
        int* totals = base_g + NT1 * 256;
        unsigned short* WAdT = (unsigned short*)(totals + 128);
        uint4* WAbf4 = (uint4*)(WAdT + WADT_N);
        unsigned short* fxA  = (unsigned short*)(WAbf4 + WABF_T);
        unsigned short* errA = fxA + FRAG_N;
        float* v_cur = (float*)(errA + FRAG_N);
        int* bar_arr = (int*)(v_cur + NVB);   // dedicated region

        k_cnt<<<NBLK, 256, 0, stream>>>(dst, cnt_g, fxA, errA, vals, v_cur,
                                        out, WAdT, bar_arr);
        k_scan_a<<<NT1, 256, 0, stream>>>(cnt_g, base_g, totals);
        k_place<<<NBLK, 256, 0, stream>>>(src, dst, wts, base_g, totals, pk_g);
        k_build<<<NT1, 256, 0, stream>>>(pk_g, totals, WAbf4, WAdT);
        k_loop<<<NBLK_P, 512, 0, stream>>>(WAbf4, WAdT, fxA, errA, v_cur, out,
                                           bar_arr);
    } else {
        float* v_cur = (float*)d_ws;
        unsigned short* fx_g  = (unsigned short*)(v_cur + NVB);
        unsigned short* err_g = fx_g + NVB;
        int* rp_dst  = (int*)(err_g + NVB);
        int* rp_src  = rp_dst + 2048;
        int* cur_dst = rp_src + 2048;
        int* cur_src = cur_dst + 2048;
        unsigned* pk_dst = (unsigned*)(cur_src + 2048);
        unsigned* pk_src = pk_dst + N_E;

        k_zero_i32<<<16, 256, 0, stream>>>(cur_dst, 4096);
        k_hist<<<EB, 256, 0, stream>>>(src, dst, cur_dst, cur_src);
        k_scan<<<1, 1024, 0, stream>>>(cur_dst, rp_dst, cur_src, rp_src);
        k_scatter<<<EB, 256, 0, stream>>>(src, dst, wts, cur_dst, cur_src,
                                          pk_dst, pk_src);
        k_cast_in<<<250, 256, 0, stream>>>(vals, v_cur);
        for (int t = 0; t < T_STEPS; ++t) {
            k_fx_csr<<<250, 256, 0, stream>>>(v_cur, fx_g);
            k_pred_err<<<500, 256, 0, stream>>>(v_cur, fx_g, rp_dst, pk_dst, err_g);
            k_back_upd<<<304, 256, 0, stream>>>(fx_g, err_g, rp_src, pk_src, v_cur);
        }
        k_out_fb<<<250, 256, 0, stream>>>(v_cur, out);
    }
}

// Round 9
// 146.889 us; speedup vs baseline: 1.1560x; 1.0180x over previous
//
#include <hip/hip_runtime.h>
#include <hip/hip_bf16.h>

// PCGraphConv: iterative predictive-coding message passing.
// N_V=2000, N_SENS=784, N_E=500000, BATCH=32, T=5, lr=0.1.
// R21 = R20 resubmit (round 8 failed with a container/infra error, no
// kernel verdict; precedent R16->R17 resolved identically).
// R20 = R19 (149.5us: 4-kernel chain + 250-block fence-free persistent
// loop) + two changes:
//  1) sensory-const split: sensory fx (k<784) is CLAMPED -> pred_const
//     computed once in phase-0 (chunks 0..24, chunk-24 interior lane-groups
//     masked; boundary 784 = lane-group aligned), kept in 4 VGPRs of the
//     w==0 wave (block-local, no barrier). Per-step phase-1 streams only
//     chunks 24..62 (39/63 of A bytes).
//  2) k_build at 512 threads (1 block/CU at 129KB LDS either way; halves
//     the zero/scatter/emit iteration counts).
// Fallback: proven R4 CSR path if ws too small.

#define N_V     2000
#define N_SENS  784
#define N_INT   (N_V - N_SENS)   // 1216
#define N_E     500000
#define T_STEPS 5
#define LR_VAL  0.1f
#define NVB     (N_V * 32)       // 64000
#define NVH     (N_V * 16)       // 32000
#define KP      2016             // padded K (63 chunks of 32)
#define NCH     63               // K chunks
#define NT1     125              // dst tiles (125*16 = 2000)
#define NT2     76               // interior src tiles (76*16 = 1216)
#define FRAG_N  (2 * NCH * 64 * 8)   // 64512 u16 per A-frag table
#define NBLK    250              // sort blocks
#define EPB     2000             // edges per sort block
#define NBLK_P  250              // persistent blocks (tile x batch-half)
#define BAR_STRIDE 32            // ints between arrival slots (128 B)
#define BAR_N   ((NBLK_P + 1) * BAR_STRIDE)
#define C_SENS  24               // chunk containing the 784 boundary

typedef float  f32x4 __attribute__((ext_vector_type(4)));
typedef short  s16x8 __attribute__((ext_vector_type(8)));
typedef unsigned long long u64;

__device__ __forceinline__ float bits_to_f32(unsigned u) {
    union { unsigned u; float f; } c; c.u = u; return c.f;
}
__device__ __forceinline__ unsigned f32_to_bits(float f) {
    union { float f; unsigned u; } c; c.f = f; return c.u;
}
__device__ __forceinline__ unsigned short f32_to_bf16(float f) {
    unsigned u = f32_to_bits(f);
    return (unsigned short)((u + 0x7FFFu + ((u >> 16) & 1u)) >> 16);  // RNE
}
__device__ __forceinline__ float bf16_to_f32(unsigned short s) {
    return bits_to_f32((unsigned)s << 16);
}

// ---- coherent (L2-bypassing) access helpers: relaxed agent atomics ----
__device__ __forceinline__ u64 ald64(const void* p) {
    return __hip_atomic_load((const u64*)p, __ATOMIC_RELAXED,
                             __HIP_MEMORY_SCOPE_AGENT);
}
__device__ __forceinline__ void ast64(void* p, u64 v) {
    __hip_atomic_store((u64*)p, v, __ATOMIC_RELAXED, __HIP_MEMORY_SCOPE_AGENT);
}
__device__ __forceinline__ unsigned short ald16(const unsigned short* p) {
    return __hip_atomic_load(p, __ATOMIC_RELAXED, __HIP_MEMORY_SCOPE_AGENT);
}
__device__ __forceinline__ void ast16(unsigned short* p, unsigned short v) {
    __hip_atomic_store(p, v, __ATOMIC_RELAXED, __HIP_MEMORY_SCOPE_AGENT);
}
// explicit system-coherent scalar ops for the barrier words
__device__ __forceinline__ int cohld(const int* p) {
    int v;
    asm volatile("global_load_dword %0, %1, off sc0 sc1\n\ts_waitcnt vmcnt(0)"
                 : "=v"(v) : "v"(p) : "memory");
    return v;
}
__device__ __forceinline__ void cohst(int* p, int v) {
    asm volatile("global_store_dword %0, %1, off sc0 sc1"
                 :: "v"(p), "v"(v) : "memory");
}

// A-fragment u16 index for element (k, b) of fx/err tables (m = b&15).
__device__ __forceinline__ int aposKB(int k, int b) {
    int c = k >> 5, q = (k >> 3) & 3, j = k & 7;
    int h = b >> 4, m = b & 15;
    return (((h * NCH + c) * 64) + q * 16 + m) * 8 + j;
}

// ------------------------- dense/MFMA path -------------------------------

// histogram edges by dst-tile (cnt_g layout [tile][block]) + merged init:
// v_cur/fxA/out from vin; zero frag pads, WAdT pad rows, barrier slots.
__global__ __launch_bounds__(256) void k_cnt(const int* __restrict__ dst,
                                             int* __restrict__ cnt_g,
                                             unsigned short* __restrict__ fxA,
                                             unsigned short* __restrict__ errA,
                                             const float* __restrict__ vin,
                                             float* __restrict__ v,
                                             float* __restrict__ out,
                                             unsigned short* __restrict__ WAdT,
                                             int* __restrict__ bar) {
    __shared__ int cnt[NT1];
    int b = blockIdx.x;
    int t = b * 256 + threadIdx.x;
    {   // zero pad slots k in [2000,2016) of both frag tables
        if (t < 16 * 32) {
            int k = 2000 + (t >> 5), bb = t & 31;
            fxA[aposKB(k, bb)] = 0;
            errA[aposKB(k, bb)] = 0;
        }
        // zero WAdT pad rows k in [2000,2016) for all 1216 columns
        if (t < N_INT * 2) {
            uint4 z = {0u, 0u, 0u, 0u};
            *(uint4*)(WAdT + (size_t)(t >> 1) * KP + 2000 + (t & 1) * 8) = z;
        }
        // zero barrier slots + go word
        if (t < BAR_N) bar[t] = 0;
    }
    // merged k_init: coalesced read of vin, scattered L2-hot writes
    if (t < NVB) {
        float x = vin[t];
        int bb = t / N_V;
        int i = t - bb * N_V;
        v[(i << 5) + bb] = x;
        fxA[aposKB(i, bb)] = f32_to_bf16(tanhf(x));
        if (i < N_SENS) out[t] = x;
    }
    for (int i = threadIdx.x; i < NT1; i += 256) cnt[i] = 0;
    __syncthreads();
    int base = b * EPB;
    for (int e = base + threadIdx.x; e < base + EPB; e += 256)
        atomicAdd(&cnt[dst[e] >> 4], 1);
    __syncthreads();
    for (int tt = threadIdx.x; tt < NT1; tt += 256)
        cnt_g[tt * 256 + b] = cnt[tt];
}

// per-tile exclusive scan over blocks; totals[t] = tile edge count
__global__ __launch_bounds__(256) void k_scan_a(const int* __restrict__ cnt_g,
                                                int* __restrict__ base_g,
                                                int* __restrict__ totals) {
    __shared__ int sh[256];
    int t = blockIdx.x, tid = threadIdx.x;
    int v = (tid < NBLK) ? cnt_g[t * 256 + tid] : 0;
    sh[tid] = v;
    __syncthreads();
    for (int off = 1; off < 256; off <<= 1) {
        int x = (tid >= off) ? sh[tid - off] : 0;
        __syncthreads();
        sh[tid] += x;
        __syncthreads();
    }
    if (tid < NBLK) base_g[t * 256 + tid] = sh[tid] - v;   // exclusive
    if (tid == 255) totals[t] = sh[255];
}

// place edges into sorted order: pk = (bf16w<<16)|(row4<<11)|src
__global__ __launch_bounds__(256) void k_place(
        const int* __restrict__ src, const int* __restrict__ dst,
        const float* __restrict__ w, const int* __restrict__ base_g,
        const int* __restrict__ totals, unsigned* __restrict__ pk_g) {
    __shared__ int cur[NT1];
    __shared__ int ts[NT1];
    int b = blockIdx.x;
    if (threadIdx.x == 0) {
        int a = 0;
        for (int t = 0; t < NT1; ++t) { ts[t] = a; a += totals[t]; }
    }
    __syncthreads();
    for (int t = threadIdx.x; t < NT1; t += 256)
        cur[t] = ts[t] + base_g[t * 256 + b];
    __syncthreads();
    int base = b * EPB;
    for (int e = base + threadIdx.x; e < base + EPB; e += 256) {
        int d = dst[e];
        unsigned pk = ((unsigned)f32_to_bf16(w[e]) << 16)
                    | ((unsigned)(d & 15) << 11) | (unsigned)src[e];
        int p = atomicAdd(&cur[d >> 4], 1);
        pk_g[p] = pk;
    }
}

// build WAbf fragments + TRANSPOSED dense bf16 WAdT from sorted edges.
// One block per tile, 512 threads: acc[16][KP] = 129 KB LDS.
__global__ __launch_bounds__(512) void k_build(
        const unsigned* __restrict__ pk_g, const int* __restrict__ totals,
        uint4* __restrict__ WAbf4, unsigned short* __restrict__ WAdT) {
    __shared__ float acc[16][KP];   // 129 KB
    __shared__ int ts[NT1 + 1];
    int tile = blockIdx.x;
    for (int i = threadIdx.x; i < 16 * KP / 4; i += 512)
        ((float4*)&acc[0][0])[i] = make_float4(0.f, 0.f, 0.f, 0.f);
    if (threadIdx.x == 0) {
        int a = 0;
        for (int t = 0; t < NT1; ++t) { ts[t] = a; a += totals[t]; }
        ts[NT1] = a;
    }
    __syncthreads();
    int beg = ts[tile], end = ts[tile + 1];
    for (int e = beg + threadIdx.x; e < end; e += 512) {
        unsigned pk = pk_g[e];
        int row = (int)((pk >> 11) & 15u);
        atomicAdd(&acc[row][pk & 0x7FFu], bf16_to_f32((unsigned short)(pk >> 16)));
    }
    __syncthreads();
    // emit WAbf fragments (all 16 rows)
    for (int i = threadIdx.x; i < 16 * 252; i += 512) {
        int m = i / 252, g = i - m * 252;
        int c = g >> 2, q = g & 3;
        int col = g * 8;
        unsigned short r[8];
        #pragma unroll
        for (int j = 0; j < 8; ++j) r[j] = f32_to_bf16(acc[m][col + j]);
        WAbf4[((tile * NCH + c) * 64) + q * 16 + m] = *(const uint4*)r;
    }
    // emit WAdT columns j in [784,2000): 16 bf16 (this tile's dst rows)
    for (int i = threadIdx.x; i < N_INT; i += 512) {
        int j = N_SENS + i;
        unsigned short r[16];
        #pragma unroll
        for (int m = 0; m < 16; ++m) r[m] = f32_to_bf16(acc[m][j]);
        uint4* p = (uint4*)(WAdT + (size_t)i * KP + tile * 16);
        p[0] = *(const uint4*)r;
        p[1] = *(const uint4*)(r + 8);
    }
}

// Fence-free device barrier (epoch-based, monotonic). Proven R15.
__device__ __forceinline__ void gbar(int* arr, int epoch, int bx, int tid) {
    asm volatile("s_waitcnt vmcnt(0) lgkmcnt(0)" ::: "memory");
    __syncthreads();
    if (bx == 0) {
        if (tid == 0) cohst(&arr[0], epoch);
        if (tid < NBLK_P) {
            while (cohld(&arr[tid * BAR_STRIDE]) < epoch)
                __builtin_amdgcn_s_sleep(2);
        }
        __syncthreads();
        if (tid == 0) cohst(&arr[NBLK_P * BAR_STRIDE], epoch);  // go
    } else {
        if (tid == 0) {
            cohst(&arr[bx * BAR_STRIDE], epoch);
            while (cohld(&arr[NBLK_P * BAR_STRIDE]) < epoch)
                __builtin_amdgcn_s_sleep(2);
        }
        __syncthreads();
    }
}

// persistent T-loop. 250 blocks x 512 threads: tile = bx>>1, half = bx&1.
// phase0 (once, no barrier): pred_const = sensory-only QK (chunks 0..24,
//   chunk 24 interior lane-groups masked), kept in w==0 VGPRs.
// phase1 (all 250):  err = v - (pred_const + interior fx.WA^T), chunks 24..62.
// phase2 (bx < 152): back = err.WB^T + v update (full K).
__global__ __launch_bounds__(512, 1) void k_loop(
        const uint4* __restrict__ WAbf4, const unsigned short* __restrict__ WAdT,
        unsigned short* fxA, unsigned short* errA,
        float* v_cur, float* __restrict__ out, int* arr) {
    __shared__ uint4 WldsA[NCH * 64];   // 64512 B
    __shared__ uint4 WldsB[NCH * 64];   // 64512 B
    __shared__ float red[2600];         // 10400 B
    const int bx = blockIdx.x, tid = threadIdx.x;
    const int tile = bx >> 1, h = bx & 1;
    {
        const uint4* Wg = WAbf4 + (size_t)tile * (NCH * 64);
        for (int i = tid; i < NCH * 64; i += 512) WldsA[i] = Wg[i];
        if (bx < 2 * NT2) {
            for (int i = tid; i < NCH * 64; i += 512) {
                int c = i >> 6, ll = i & 63;
                int row = tile * 16 + (ll & 15);
                int k0 = c * 32 + (ll >> 4) * 8;
                WldsB[i] = *(const uint4*)(WAdT + (size_t)row * KP + k0);
            }
        }
    }
    const int w = tid >> 6, l = tid & 63;
    const int grp = l >> 4;
    float* my = &red[w * 325 + l * 5];
    int epoch = 0;
    float pc[4] = {0.f, 0.f, 0.f, 0.f};   // pred_const, valid in w==0 lanes
    __syncthreads();

    // ---------------- phase 0: pred_const (block-local, once) -----------
    {
        const int cb0 = w * 4;               // chunks cb0..cb0+3, guard <25
        const u64* ap = (const u64*)fxA
                      + ((size_t)h * (NCH * 64) + cb0 * 64 + l) * 2;
        u64 f0[4], f1[4];
        #pragma unroll
        for (int cc = 0; cc < 4; ++cc)
            if (cb0 + cc <= C_SENS) {
                f0[cc] = ald64(ap + cc * 128);
                f1[cc] = ald64(ap + cc * 128 + 1);
                if (cb0 + cc == C_SENS && grp >= 2) { f0[cc] = 0; f1[cc] = 0; }
            }
        __builtin_amdgcn_sched_barrier(0);
        f32x4 acc = {0.f, 0.f, 0.f, 0.f};
        #pragma unroll
        for (int cc = 0; cc < 4; ++cc)
            if (cb0 + cc <= C_SENS) {
                u64 d[2] = {f0[cc], f1[cc]};
                uint4 bfrag = WldsA[(cb0 + cc) * 64 + l];
                acc = __builtin_amdgcn_mfma_f32_16x16x32_bf16(
                          *(s16x8*)d, *(s16x8*)&bfrag, acc, 0, 0, 0);
            }
        #pragma unroll
        for (int r = 0; r < 4; ++r) my[r] = acc[r];
        __syncthreads();
        if (w == 0) {
            #pragma unroll
            for (int r = 0; r < 4; ++r) {
                float sum = 0.f;
                #pragma unroll
                for (int ww = 0; ww < 8; ++ww)
                    sum += red[ww * 325 + l * 5 + r];
                pc[r] = sum;
            }
        }
        __syncthreads();   // red reused by phase 1 below
    }

    for (int t = 0; t < T_STEPS; ++t) {
        // ---------------- phase 1: err, interior chunks 24..62 ----------
        {
            const int cb = C_SENS + w * 5;   // 24,29,..,59; guard < NCH
            const u64* ap = (const u64*)fxA
                          + ((size_t)h * (NCH * 64) + cb * 64 + l) * 2;
            u64 f0[5], f1[5];
            #pragma unroll
            for (int cc = 0; cc < 5; ++cc)
                if (cb + cc < NCH) {
                    f0[cc] = ald64(ap + cc * 128);
                    f1[cc] = ald64(ap + cc * 128 + 1);
                    if (cb + cc == C_SENS && grp < 2) { f0[cc] = 0; f1[cc] = 0; }
                }
            __builtin_amdgcn_sched_barrier(0);
            f32x4 acc = {0.f, 0.f, 0.f, 0.f};
            #pragma unroll
            for (int cc = 0; cc < 5; ++cc)
                if (cb + cc < NCH) {
                    u64 d[2] = {f0[cc], f1[cc]};
                    uint4 bfrag = WldsA[(cb + cc) * 64 + l];
                    acc = __builtin_amdgcn_mfma_f32_16x16x32_bf16(
                              *(s16x8*)d, *(s16x8*)&bfrag, acc, 0, 0, 0);
                }
            #pragma unroll
            for (int r = 0; r < 4; ++r) my[r] = acc[r];
            __syncthreads();
            if (w == 0) {
                float s[4];
                #pragma unroll
                for (int r = 0; r < 4; ++r) {
                    float sum = pc[r];
                    #pragma unroll
                    for (int ww = 0; ww < 8; ++ww)
                        sum += red[ww * 325 + l * 5 + r];
                    s[r] = sum;
                }
                int i = tile * 16 + (l & 15);
                int q = l >> 4;
                int c2 = i >> 5, q2 = (i >> 3) & 3, j2 = i & 7;
                const float* vp = v_cur + (i << 5) + h * 16 + q * 4;
                union { u64 u[2]; float f[4]; } vu;
                vu.u[0] = ald64(vp);
                vu.u[1] = ald64(vp + 2);
                int base = ((h * NCH + c2) * 64 + q2 * 16) * 8 + j2;
                #pragma unroll
                for (int r = 0; r < 4; ++r)
                    ast16(&errA[base + (q * 4 + r) * 8],
                          f32_to_bf16(vu.f[r] - s[r]));
            }
        }
        ++epoch; gbar(arr, epoch, bx, tid);

        // ---------------- phase 2: back + update (bx < 152) ------------
        if (bx < 2 * NT2) {
            const int cb = w * 8;
            const u64* ap = (const u64*)errA
                          + ((size_t)h * (NCH * 64) + cb * 64 + l) * 2;
            u64 f0[8], f1[8];
            #pragma unroll
            for (int cc = 0; cc < 8; ++cc)
                if (cb + cc < NCH) {
                    f0[cc] = ald64(ap + cc * 128);
                    f1[cc] = ald64(ap + cc * 128 + 1);
                }
            __builtin_amdgcn_sched_barrier(0);
            f32x4 acc = {0.f, 0.f, 0.f, 0.f};
            #pragma unroll
            for (int cc = 0; cc < 8; ++cc)
                if (cb + cc < NCH) {
                    u64 d[2] = {f0[cc], f1[cc]};
                    uint4 bfrag = WldsB[(cb + cc) * 64 + l];
                    acc = __builtin_amdgcn_mfma_f32_16x16x32_bf16(
                              *(s16x8*)d, *(s16x8*)&bfrag, acc, 0, 0, 0);
                }
            #pragma unroll
            for (int r = 0; r < 4; ++r) my[r] = acc[r];
            __syncthreads();
            if (w == 0) {
                float s[4];
                #pragma unroll
                for (int r = 0; r < 4; ++r) {
                    float sum = 0.f;
                    #pragma unroll
                    for (int ww = 0; ww < 8; ++ww)
                        sum += red[ww * 325 + l * 5 + r];
                    s[r] = sum;
                }
                int j = N_SENS + tile * 16 + (l & 15);
                int q = l >> 4;
                int c2 = j >> 5, q2 = (j >> 3) & 3, j2 = j & 7;
                float* vp = v_cur + (j << 5) + h * 16 + q * 4;
                union { u64 u[2]; float f[4]; } vu;
                vu.u[0] = ald64(vp);
                vu.u[1] = ald64(vp + 2);
                int base = ((h * NCH + c2) * 64 + q2 * 16) * 8 + j2;
                #pragma unroll
                for (int r = 0; r < 4; ++r) {
                    float e0 = bf16_to_f32(ald16(&errA[base + (q * 4 + r) * 8]));
                    float fxv = tanhf(vu.f[r]);
                    float vn = vu.f[r] - LR_VAL * (e0 - (1.f - fxv * fxv) * s[r]);
                    vu.f[r] = vn;
                    ast16(&fxA[base + (q * 4 + r) * 8], f32_to_bf16(tanhf(vn)));
                }
                ast64(vp, vu.u[0]);
                ast64(vp + 2, vu.u[1]);
                if (t == T_STEPS - 1) {
                    #pragma unroll
                    for (int r = 0; r < 4; ++r) {
                        int b = h * 16 + q * 4 + r;
                        out[b * N_V + j] = vu.f[r];
                    }
                }
            }
        }
        if (t < T_STEPS - 1) { ++epoch; gbar(arr, epoch, bx, tid); }
    }
}

// ------------------------- fallback path (R4 CSR, proven) ----------------

__global__ void k_zero_i32(int* a, int n) {
    int t = blockIdx.x * blockDim.x + threadIdx.x;
    if (t < n) a[t] = 0;
}

__global__ void k_hist(const int* __restrict__ src, const int* __restrict__ dst,
                       int* cnt_dst, int* cnt_src) {
    int e = blockIdx.x * blockDim.x + threadIdx.x;
    if (e < N_E) {
        atomicAdd(&cnt_dst[dst[e]], 1);
        atomicAdd(&cnt_src[src[e]], 1);
    }
}

__global__ __launch_bounds__(1024) void k_scan(int* cnt_a, int* rp_a,
                                               int* cnt_b, int* rp_b) {
    __shared__ int sh[1024];
    int t = threadIdx.x;
    for (int pass = 0; pass < 2; ++pass) {
        int* cnt = pass ? cnt_b : cnt_a;
        int* rp  = pass ? rp_b  : rp_a;
        int i0 = 2 * t, i1 = 2 * t + 1;
        int c0 = (i0 < N_V) ? cnt[i0] : 0;
        int c1 = (i1 < N_V) ? cnt[i1] : 0;
        __syncthreads();
        sh[t] = c0 + c1;
        __syncthreads();
        for (int off = 1; off < 1024; off <<= 1) {
            int v = (t >= off) ? sh[t - off] : 0;
            __syncthreads();
            sh[t] += v;
            __syncthreads();
        }
        int incl = sh[t];
        int e0 = incl - (c0 + c1);
        int e1 = e0 + c0;
        if (i0 <= N_V) rp[i0] = e0;
        if (i1 <= N_V) rp[i1] = e1;
        if (i0 < N_V) cnt[i0] = e0;
        if (i1 < N_V) cnt[i1] = e1;
    }
}

__global__ void k_scatter(const int* __restrict__ src, const int* __restrict__ dst,
                          const float* __restrict__ w,
                          int* cur_dst, int* cur_src,
                          unsigned* __restrict__ pk_dst, unsigned* __restrict__ pk_src) {
    int e = blockIdx.x * blockDim.x + threadIdx.x;
    if (e < N_E) {
        int s = src[e], d = dst[e];
        unsigned wbits = (unsigned)f32_to_bf16(w[e]);
        int p = atomicAdd(&cur_dst[d], 1);
        pk_dst[p] = (wbits << 16) | (unsigned)s;
        int q = atomicAdd(&cur_src[s], 1);
        pk_src[q] = (wbits << 16) | (unsigned)d;
    }
}

__global__ void k_cast_in(const float* __restrict__ vin, float* __restrict__ v) {
    int t = blockIdx.x * blockDim.x + threadIdx.x;
    if (t < NVB) {
        int i = t >> 5, b = t & 31;
        v[t] = vin[b * N_V + i];
    }
}

__global__ void k_fx_csr(const float* __restrict__ v, unsigned short* __restrict__ fx) {
    int t = blockIdx.x * blockDim.x + threadIdx.x;
    if (t < NVB) {
        int i = t >> 5, b = t & 31;
        int h = b >> 4, b16 = b & 15;
        fx[h * NVH + i * 16 + b16] = f32_to_bf16(tanhf(v[t]));
    }
}

__global__ __launch_bounds__(256) void k_pred_err(
        const float* __restrict__ v, const unsigned short* __restrict__ fx,
        const int* __restrict__ rp, const unsigned* __restrict__ pk,
        unsigned short* __restrict__ err) {
    __shared__ unsigned short tab[NVH];
    int h  = blockIdx.x / 250;
    int vg = blockIdx.x % 250;
    {
        const uint4* g = (const uint4*)(fx + h * NVH);
        uint4* l = (uint4*)tab;
        for (int i = threadIdx.x; i < NVH / 8; i += 256) l[i] = g[i];
    }
    __syncthreads();
    int wave = threadIdx.x >> 6;
    int lane = threadIdx.x & 63;
    int b16 = lane & 15, epar = lane >> 4;
    for (int k = 0; k < 2; ++k) {
        int vid = vg * 8 + wave * 2 + k;
        int beg = rp[vid], end = rp[vid + 1];
        float sum = 0.f;
        for (int e = beg + epar; e < end; e += 4) {
            unsigned p = pk[e];
            float w = bits_to_f32(p & 0xFFFF0000u);
            int nb = (int)(p & 0xFFFFu);
            sum += w * bf16_to_f32(tab[nb * 16 + b16]);
        }
        sum += __shfl_xor(sum, 16, 64);
        sum += __shfl_xor(sum, 32, 64);
        if (epar == 0) {
            float vo = v[(vid << 5) + h * 16 + b16];
            err[h * NVH + vid * 16 + b16] = f32_to_bf16(vo - sum);
        }
    }
}

__global__ __launch_bounds__(256) void k_back_upd(
        const unsigned short* __restrict__ fx, const unsigned short* __restrict__ err,
        const int* __restrict__ rp, const unsigned* __restrict__ pk,
        float* __restrict__ v) {
    __shared__ unsigned short tab[NVH];
    int h  = blockIdx.x / 152;
    int vg = blockIdx.x % 152;
    {
        const uint4* g = (const uint4*)(err + h * NVH);
        uint4* l = (uint4*)tab;
        for (int i = threadIdx.x; i < NVH / 8; i += 256) l[i] = g[i];
    }
    __syncthreads();
    int wave = threadIdx.x >> 6;
    int lane = threadIdx.x & 63;
    int b16 = lane & 15, epar = lane >> 4;
    for (int k = 0; k < 2; ++k) {
        int vid = N_SENS + vg * 8 + wave * 2 + k;
        if (vid >= N_V) continue;
        int beg = rp[vid], end = rp[vid + 1];
        float sum = 0.f;
        for (int e = beg + epar; e < end; e += 4) {
            unsigned p = pk[e];
            float w = bits_to_f32(p & 0xFFFF0000u);
            int nb = (int)(p & 0xFFFFu);
            sum += w * bf16_to_f32(tab[nb * 16 + b16]);
        }
        sum += __shfl_xor(sum, 16, 64);
        sum += __shfl_xor(sum, 32, 64);
        if (epar == 0) {
            float e0  = bf16_to_f32(tab[vid * 16 + b16]);
            float fxv = bf16_to_f32(fx[h * NVH + vid * 16 + b16]);
            float dv = e0 - (1.f - fxv * fxv) * sum;
            v[(vid << 5) + h * 16 + b16] -= LR_VAL * dv;
        }
    }
}

__global__ void k_out_fb(const float* __restrict__ v, float* __restrict__ out) {
    int t = blockIdx.x * blockDim.x + threadIdx.x;
    if (t < NVB) {
        int b = t / N_V;
        int i = t - b * N_V;
        out[t] = v[(i << 5) + b];
    }
}

// ------------------------- host -----------------------------------------

extern "C" void kernel_launch(void* const* d_in, const int* in_sizes, int n_in,
                              void* d_out, int out_size, void* d_ws, size_t ws_size,
                              hipStream_t stream) {
    const float* vals = (const float*)d_in[0];
    const float* wts  = (const float*)d_in[1];
    const int* ei = (const int*)d_in[2];
    const int* src = ei;
    const int* dst = ei + N_E;
    float* out = (float*)d_out;

    const int EB = (N_E + 255) / 256;

    // ws layout: pk_g | cnt_g | base_g | totals | WAdT | WAbf | fxA | errA
    //            | v_cur | bar   (~20.5 MB)
    const size_t WABF_T = (size_t)NT1 * NCH * 64;        // uint4 count
    const size_t WADT_N = (size_t)N_INT * KP;            // u16 count
    const size_t need = (size_t)N_E * 4 + 2 * NT1 * 256 * 4 + 512
                      + WADT_N * 2 + WABF_T * 16
                      + 2 * (size_t)FRAG_N * 2 + NVB * 4
                      + (size_t)BAR_N * 4 + 256;

    if (ws_size >= need) {
        unsigned* pk_g = (unsigned*)d_ws;
        int* cnt_g  = (int*)(pk_g + N_E);
        int* base_g = cnt_g + NT1 * 256;
        int* totals = base_g + NT1 * 256;
        unsigned short* WAdT = (unsigned short*)(totals + 128);
        uint4* WAbf4 = (uint4*)(WAdT + WADT_N);
        unsigned short* fxA  = (unsigned short*)(WAbf4 + WABF_T);
        unsigned short* errA = fxA + FRAG_N;
        float* v_cur = (float*)(errA + FRAG_N);
        int* bar_arr = (int*)(v_cur + NVB);   // dedicated region

        k_cnt<<<NBLK, 256, 0, stream>>>(dst, cnt_g, fxA, errA, vals, v_cur,
                                        out, WAdT, bar_arr);
        k_scan_a<<<NT1, 256, 0, stream>>>(cnt_g, base_g, totals);
        k_place<<<NBLK, 256, 0, stream>>>(src, dst, wts, base_g, totals, pk_g);
        k_build<<<NT1, 512, 0, stream>>>(pk_g, totals, WAbf4, WAdT);
        k_loop<<<NBLK_P, 512, 0, stream>>>(WAbf4, WAdT, fxA, errA, v_cur, out,
                                           bar_arr);
    } else {
        float* v_cur = (float*)d_ws;
        unsigned short* fx_g  = (unsigned short*)(v_cur + NVB);
        unsigned short* err_g = fx_g + NVB;
        int* rp_dst  = (int*)(err_g + NVB);
        int* rp_src  = rp_dst + 2048;
        int* cur_dst = rp_src + 2048;
        int* cur_src = cur_dst + 2048;
        unsigned* pk_dst = (unsigned*)(cur_src + 2048);
        unsigned* pk_src = pk_dst + N_E;

        k_zero_i32<<<16, 256, 0, stream>>>(cur_dst, 4096);
        k_hist<<<EB, 256, 0, stream>>>(src, dst, cur_dst, cur_src);
        k_scan<<<1, 1024, 0, stream>>>(cur_dst, rp_dst, cur_src, rp_src);
        k_scatter<<<EB, 256, 0, stream>>>(src, dst, wts, cur_dst, cur_src,
                                          pk_dst, pk_src);
        k_cast_in<<<250, 256, 0, stream>>>(vals, v_cur);
        for (int t = 0; t < T_STEPS; ++t) {
            k_fx_csr<<<250, 256, 0, stream>>>(v_cur, fx_g);
            k_pred_err<<<500, 256, 0, stream>>>(v_cur, fx_g, rp_dst, pk_dst, err_g);
            k_back_upd<<<304, 256, 0, stream>>>(fx_g, err_g, rp_src, pk_src, v_cur);
        }
        k_out_fb<<<250, 256, 0, stream>>>(v_cur, out);
    }
}